// Round 2
// baseline (299.042 us; speedup 1.0000x reference)
//
#include <hip/hip_runtime.h>

// NodeDropout: out[e] = values[e] if (!flag[src[e]] && !flag[dst[e]]) else 0
// E = 20M edges, N = 1M nodes.
//
// R5: force memory-level parallelism. R4 evidence: coalescing fix worked
// (main kernel ~66 us, off the top-5; fills dominate), but VGPR_Count=32
// proves the compiler serialized the 12 loads into ~4-VGPR chunks -> each
// wave stalls on vmcnt with little outstanding traffic; at 16 waves/CU
// (125 KB LDS -> 1 block/CU) that leaves us at ~76% of stream BW.
// R5 builds an explicit 2-stage software pipeline with two NAMED register
// tile sets (A/B, no runtime indexing): issue tile t+1's 12 NT loads before
// masking/storing tile t. ~115 VGPR forces real in-flight loads;
// launch_bounds(1024,4) caps at 128 so the 16-wave block still fits.

typedef int   vint4   __attribute__((ext_vector_type(4)));
typedef float vfloat4 __attribute__((ext_vector_type(4)));

__global__ __launch_bounds__(256) void pack_flags(
    const int* __restrict__ flag, unsigned int* __restrict__ packed, int n_words, int n)
{
    int w = blockIdx.x * blockDim.x + threadIdx.x;
    if (w >= n_words) return;
    int base = w * 32;
    unsigned int bits = 0;
    if (base + 32 <= n) {
        const vint4* p = (const vint4*)(flag + base);
        #pragma unroll
        for (int k = 0; k < 8; ++k) {
            vint4 f = p[k];
            bits |= (unsigned int)(f.x != 0) << (k * 4 + 0);
            bits |= (unsigned int)(f.y != 0) << (k * 4 + 1);
            bits |= (unsigned int)(f.z != 0) << (k * 4 + 2);
            bits |= (unsigned int)(f.w != 0) << (k * 4 + 3);
        }
    } else {
        for (int j = 0; j < 32 && base + j < n; ++j)
            bits |= (unsigned int)(flag[base + j] != 0) << j;
    }
    packed[w] = bits;
}

// ---------------- LDS-table main kernel ----------------

__device__ __forceinline__ float mask_lds(
    const unsigned int* tab, int s, int d, float v)
{
    unsigned int ws = tab[s >> 5];
    unsigned int wd = tab[d >> 5];
    unsigned int drop = ((ws >> (s & 31)) | (wd >> (d & 31))) & 1u;
    return drop ? 0.0f : v;
}

__device__ __forceinline__ vfloat4 mask_group(
    const unsigned int* tab, vint4 s, vint4 d, vfloat4 v)
{
    vfloat4 o;
    o.x = mask_lds(tab, s.x, d.x, v.x);
    o.y = mask_lds(tab, s.y, d.y, v.y);
    o.z = mask_lds(tab, s.z, d.z, v.z);
    o.w = mask_lds(tab, s.w, d.w, v.w);
    return o;
}

// One tile = 4 strided vec4 groups, named members only (no runtime indexing).
struct Tile {
    vint4   s0, s1, s2, s3;
    vint4   d0, d1, d2, d3;
    vfloat4 v0, v1, v2, v3;
};

__device__ __forceinline__ void load_tile(Tile& t,
    const vint4* __restrict__ src4, const vint4* __restrict__ dst4,
    const vfloat4* __restrict__ val4, int base, int T)
{
    t.s0 = __builtin_nontemporal_load(&src4[base]);
    t.s1 = __builtin_nontemporal_load(&src4[base + T]);
    t.s2 = __builtin_nontemporal_load(&src4[base + 2 * T]);
    t.s3 = __builtin_nontemporal_load(&src4[base + 3 * T]);
    t.d0 = __builtin_nontemporal_load(&dst4[base]);
    t.d1 = __builtin_nontemporal_load(&dst4[base + T]);
    t.d2 = __builtin_nontemporal_load(&dst4[base + 2 * T]);
    t.d3 = __builtin_nontemporal_load(&dst4[base + 3 * T]);
    t.v0 = __builtin_nontemporal_load(&val4[base]);
    t.v1 = __builtin_nontemporal_load(&val4[base + T]);
    t.v2 = __builtin_nontemporal_load(&val4[base + 2 * T]);
    t.v3 = __builtin_nontemporal_load(&val4[base + 3 * T]);
}

__device__ __forceinline__ void cs_tile(const Tile& t,
    const unsigned int* tab, vfloat4* __restrict__ out4, int base, int T)
{
    vfloat4 o0 = mask_group(tab, t.s0, t.d0, t.v0);
    vfloat4 o1 = mask_group(tab, t.s1, t.d1, t.v1);
    vfloat4 o2 = mask_group(tab, t.s2, t.d2, t.v2);
    vfloat4 o3 = mask_group(tab, t.s3, t.d3, t.v3);
    __builtin_nontemporal_store(o0, &out4[base]);
    __builtin_nontemporal_store(o1, &out4[base + T]);
    __builtin_nontemporal_store(o2, &out4[base + 2 * T]);
    __builtin_nontemporal_store(o3, &out4[base + 3 * T]);
}

__global__ __launch_bounds__(1024, 4) void node_dropout_lds(
    const vint4* __restrict__ src4,
    const vint4* __restrict__ dst4,
    const vfloat4* __restrict__ val4,
    const unsigned int* __restrict__ packed,
    vfloat4* __restrict__ out4,
    int n_words,
    int n4)   // number of 4-edge (vec4) groups
{
    extern __shared__ unsigned int tab[];
    // Vectorized table fill (coalesced 16B loads), scalar remainder.
    {
        const int nw4 = n_words >> 2;
        const vint4* p4 = (const vint4*)packed;
        vint4* t4 = (vint4*)tab;
        for (int w = threadIdx.x; w < nw4; w += blockDim.x)
            t4[w] = p4[w];
        for (int w = (nw4 << 2) + threadIdx.x; w < n_words; w += blockDim.x)
            tab[w] = packed[w];
    }
    __syncthreads();

    const int T = gridDim.x * blockDim.x;
    const int p = blockIdx.x * blockDim.x + threadIdx.x;
    const int step = 4 * T;
    const int nfull = n4 / step;   // grid-uniform full-tile count per thread

    Tile A, B;
    if (nfull > 0) {
        load_tile(A, src4, dst4, val4, p, T);
        int t = 0;
        for (; t + 2 < nfull; t += 2) {
            load_tile(B, src4, dst4, val4, p + (t + 1) * step, T);
            cs_tile(A, tab, out4, p + t * step, T);
            load_tile(A, src4, dst4, val4, p + (t + 2) * step, T);
            cs_tile(B, tab, out4, p + (t + 1) * step, T);
        }
        if (t + 1 < nfull) {
            load_tile(B, src4, dst4, val4, p + (t + 1) * step, T);
            cs_tile(A, tab, out4, p + t * step, T);
            cs_tile(B, tab, out4, p + (t + 1) * step, T);
        } else {
            cs_tile(A, tab, out4, p + t * step, T);
        }
    }
    // Cleanup: remaining groups one at a time (still lane-contiguous).
    for (int i = p + nfull * step; i < n4; i += T) {
        vint4 s = __builtin_nontemporal_load(&src4[i]);
        vint4 d = __builtin_nontemporal_load(&dst4[i]);
        vfloat4 v = __builtin_nontemporal_load(&val4[i]);
        vfloat4 o = mask_group(tab, s, d, v);
        __builtin_nontemporal_store(o, &out4[i]);
    }
}

// ---------------- R2 fallback kernel (global packed table) ----------------

__device__ __forceinline__ float mask_one(
    const unsigned int* __restrict__ packed, int s, int d, float v)
{
    unsigned int ws = packed[s >> 5];
    unsigned int wd = packed[d >> 5];
    unsigned int drop = ((ws >> (s & 31)) | (wd >> (d & 31))) & 1u;
    return drop ? 0.0f : v;
}

__global__ __launch_bounds__(256) void node_dropout_packed(
    const vint4* __restrict__ src4,
    const vint4* __restrict__ dst4,
    const vfloat4* __restrict__ val4,
    const unsigned int* __restrict__ packed,
    vfloat4* __restrict__ out4,
    int n4)
{
    const int T = gridDim.x * blockDim.x;
    for (int i = blockIdx.x * blockDim.x + threadIdx.x; i < n4; i += T) {
        vint4 s = __builtin_nontemporal_load(&src4[i]);
        vint4 d = __builtin_nontemporal_load(&dst4[i]);
        vfloat4 v = __builtin_nontemporal_load(&val4[i]);
        vfloat4 o;
        o.x = mask_one(packed, s.x, d.x, v.x);
        o.y = mask_one(packed, s.y, d.y, v.y);
        o.z = mask_one(packed, s.z, d.z, v.z);
        o.w = mask_one(packed, s.w, d.w, v.w);
        __builtin_nontemporal_store(o, &out4[i]);
    }
}

// Tail: one edge per thread, unpacked flags.
__global__ __launch_bounds__(256) void node_dropout_tail(
    const int* __restrict__ src,
    const int* __restrict__ dst,
    const float* __restrict__ val,
    const int* __restrict__ flag,
    float* __restrict__ out,
    int begin, int end)
{
    int e = begin + blockIdx.x * blockDim.x + threadIdx.x;
    if (e >= end) return;
    out[e] = (flag[src[e]] | flag[dst[e]]) ? 0.0f : val[e];
}

extern "C" void kernel_launch(void* const* d_in, const int* in_sizes, int n_in,
                              void* d_out, int out_size, void* d_ws, size_t ws_size,
                              hipStream_t stream)
{
    const int* edge_index = (const int*)d_in[0];
    const float* values   = (const float*)d_in[1];
    const int* flag       = (const int*)d_in[2];
    float* out            = (float*)d_out;

    const int E = in_sizes[1];
    const int N = in_sizes[2];
    const int* src = edge_index;
    const int* dst = edge_index + E;

    const int n_words = (N + 31) / 32;
    const size_t need = (size_t)n_words * sizeof(unsigned int);
    const size_t lds_bytes = (size_t)n_words * sizeof(unsigned int);

    if (ws_size >= need) {
        unsigned int* packed = (unsigned int*)d_ws;
        pack_flags<<<(n_words + 255) / 256, 256, 0, stream>>>(flag, packed, n_words, N);

        bool lds_ok = (lds_bytes <= 160 * 1024);
        if (lds_ok && lds_bytes > 64 * 1024) {
            lds_ok = (hipFuncSetAttribute(
                          (const void*)node_dropout_lds,
                          hipFuncAttributeMaxDynamicSharedMemorySize,
                          (int)lds_bytes) == hipSuccess);
        }

        const int n4 = E / 4;
        if (lds_ok) {
            if (n4 > 0) {
                node_dropout_lds<<<256, 1024, lds_bytes, stream>>>(
                    (const vint4*)src, (const vint4*)dst, (const vfloat4*)values,
                    packed, (vfloat4*)out, n_words, n4);
            }
        } else {
            if (n4 > 0) {
                node_dropout_packed<<<512, 256, 0, stream>>>(
                    (const vint4*)src, (const vint4*)dst, (const vfloat4*)values,
                    packed, (vfloat4*)out, n4);
            }
        }
        const int tail_begin = n4 * 4;
        if (tail_begin < E) {
            node_dropout_tail<<<(E - tail_begin + 255) / 256, 256, 0, stream>>>(
                src, dst, values, flag, out, tail_begin, E);
        }
    } else {
        node_dropout_tail<<<(E + 255) / 256, 256, 0, stream>>>(
            src, dst, values, flag, out, 0, E);
    }
}

// Round 4
// 287.087 us; speedup vs baseline: 1.0416x; 1.0416x over previous
//
#include <hip/hip_runtime.h>

// NodeDropout: out[e] = values[e] if (!flag[src[e]] && !flag[dst[e]]) else 0
// E = 20M edges, N = 1M nodes.
//
// R7 == R6 resubmit (R6 bench failed on container acquisition, kernel never
// ran). R6: revert R5's explicit A/B pipeline (regressed 288->299: forced
// 24-vec4 liveness + 16% of work pushed into cleanup loop). Back to R4's
// simple 4-deep strided unroll, ONE change: per-group load order.
// R4 ordered loads s0..s3,d0..d3,v0..v3 -> consuming group0 needs loads
// #1/#5/#9 -> in-order vmcnt forces drain to vmcnt(3),(2),(1),(0): avg ~1.5
// loads in flight during the consume phase. R6 orders (s,d,v) per group ->
// group0 waits at vmcnt(9), then 6,3,0: avg ~4.5 in flight, 3x the
// consume-phase overlap, no extra liveness. Gather path (125 KB bit table
// in LDS, 1 block/CU, 16 waves) unchanged.

typedef int   vint4   __attribute__((ext_vector_type(4)));
typedef float vfloat4 __attribute__((ext_vector_type(4)));

__global__ __launch_bounds__(256) void pack_flags(
    const int* __restrict__ flag, unsigned int* __restrict__ packed, int n_words, int n)
{
    int w = blockIdx.x * blockDim.x + threadIdx.x;
    if (w >= n_words) return;
    int base = w * 32;
    unsigned int bits = 0;
    if (base + 32 <= n) {
        const vint4* p = (const vint4*)(flag + base);
        #pragma unroll
        for (int k = 0; k < 8; ++k) {
            vint4 f = p[k];
            bits |= (unsigned int)(f.x != 0) << (k * 4 + 0);
            bits |= (unsigned int)(f.y != 0) << (k * 4 + 1);
            bits |= (unsigned int)(f.z != 0) << (k * 4 + 2);
            bits |= (unsigned int)(f.w != 0) << (k * 4 + 3);
        }
    } else {
        for (int j = 0; j < 32 && base + j < n; ++j)
            bits |= (unsigned int)(flag[base + j] != 0) << j;
    }
    packed[w] = bits;
}

// ---------------- LDS-table main kernel ----------------

__device__ __forceinline__ float mask_lds(
    const unsigned int* tab, int s, int d, float v)
{
    unsigned int ws = tab[s >> 5];
    unsigned int wd = tab[d >> 5];
    unsigned int drop = ((ws >> (s & 31)) | (wd >> (d & 31))) & 1u;
    return drop ? 0.0f : v;
}

__device__ __forceinline__ vfloat4 mask_group(
    const unsigned int* tab, vint4 s, vint4 d, vfloat4 v)
{
    vfloat4 o;
    o.x = mask_lds(tab, s.x, d.x, v.x);
    o.y = mask_lds(tab, s.y, d.y, v.y);
    o.z = mask_lds(tab, s.z, d.z, v.z);
    o.w = mask_lds(tab, s.w, d.w, v.w);
    return o;
}

__global__ __launch_bounds__(1024, 4) void node_dropout_lds(
    const vint4* __restrict__ src4,
    const vint4* __restrict__ dst4,
    const vfloat4* __restrict__ val4,
    const unsigned int* __restrict__ packed,
    vfloat4* __restrict__ out4,
    int n_words,
    int n4)   // number of 4-edge (vec4) groups
{
    extern __shared__ unsigned int tab[];
    // Vectorized table fill (coalesced 16B loads), scalar remainder.
    {
        const int nw4 = n_words >> 2;
        const vint4* p4 = (const vint4*)packed;
        vint4* t4 = (vint4*)tab;
        for (int w = threadIdx.x; w < nw4; w += blockDim.x)
            t4[w] = p4[w];
        for (int w = (nw4 << 2) + threadIdx.x; w < n_words; w += blockDim.x)
            tab[w] = packed[w];
    }
    __syncthreads();

    const int T = gridDim.x * blockDim.x;
    int i = blockIdx.x * blockDim.x + threadIdx.x;

    // Main loop: 4-deep strided unroll; loads grouped (s,d,v) per group so
    // the first consume waits at vmcnt(9), not vmcnt(3).
    for (; i + 3 * T < n4; i += 4 * T) {
        const int g0 = i, g1 = i + T, g2 = i + 2 * T, g3 = i + 3 * T;

        vint4   s0 = __builtin_nontemporal_load(&src4[g0]);
        vint4   d0 = __builtin_nontemporal_load(&dst4[g0]);
        vfloat4 v0 = __builtin_nontemporal_load(&val4[g0]);
        vint4   s1 = __builtin_nontemporal_load(&src4[g1]);
        vint4   d1 = __builtin_nontemporal_load(&dst4[g1]);
        vfloat4 v1 = __builtin_nontemporal_load(&val4[g1]);
        vint4   s2 = __builtin_nontemporal_load(&src4[g2]);
        vint4   d2 = __builtin_nontemporal_load(&dst4[g2]);
        vfloat4 v2 = __builtin_nontemporal_load(&val4[g2]);
        vint4   s3 = __builtin_nontemporal_load(&src4[g3]);
        vint4   d3 = __builtin_nontemporal_load(&dst4[g3]);
        vfloat4 v3 = __builtin_nontemporal_load(&val4[g3]);

        vfloat4 o0 = mask_group(tab, s0, d0, v0);
        __builtin_nontemporal_store(o0, &out4[g0]);
        vfloat4 o1 = mask_group(tab, s1, d1, v1);
        __builtin_nontemporal_store(o1, &out4[g1]);
        vfloat4 o2 = mask_group(tab, s2, d2, v2);
        __builtin_nontemporal_store(o2, &out4[g2]);
        vfloat4 o3 = mask_group(tab, s3, d3, v3);
        __builtin_nontemporal_store(o3, &out4[g3]);
    }
    // Cleanup: one group at a time (still lane-contiguous).
    for (; i < n4; i += T) {
        vint4 s = __builtin_nontemporal_load(&src4[i]);
        vint4 d = __builtin_nontemporal_load(&dst4[i]);
        vfloat4 v = __builtin_nontemporal_load(&val4[i]);
        vfloat4 o = mask_group(tab, s, d, v);
        __builtin_nontemporal_store(o, &out4[i]);
    }
}

// ---------------- R2 fallback kernel (global packed table) ----------------

__device__ __forceinline__ float mask_one(
    const unsigned int* __restrict__ packed, int s, int d, float v)
{
    unsigned int ws = packed[s >> 5];
    unsigned int wd = packed[d >> 5];
    unsigned int drop = ((ws >> (s & 31)) | (wd >> (d & 31))) & 1u;
    return drop ? 0.0f : v;
}

__global__ __launch_bounds__(256) void node_dropout_packed(
    const vint4* __restrict__ src4,
    const vint4* __restrict__ dst4,
    const vfloat4* __restrict__ val4,
    const unsigned int* __restrict__ packed,
    vfloat4* __restrict__ out4,
    int n4)
{
    const int T = gridDim.x * blockDim.x;
    for (int i = blockIdx.x * blockDim.x + threadIdx.x; i < n4; i += T) {
        vint4 s = __builtin_nontemporal_load(&src4[i]);
        vint4 d = __builtin_nontemporal_load(&dst4[i]);
        vfloat4 v = __builtin_nontemporal_load(&val4[i]);
        vfloat4 o;
        o.x = mask_one(packed, s.x, d.x, v.x);
        o.y = mask_one(packed, s.y, d.y, v.y);
        o.z = mask_one(packed, s.z, d.z, v.z);
        o.w = mask_one(packed, s.w, d.w, v.w);
        __builtin_nontemporal_store(o, &out4[i]);
    }
}

// Tail: one edge per thread, unpacked flags.
__global__ __launch_bounds__(256) void node_dropout_tail(
    const int* __restrict__ src,
    const int* __restrict__ dst,
    const float* __restrict__ val,
    const int* __restrict__ flag,
    float* __restrict__ out,
    int begin, int end)
{
    int e = begin + blockIdx.x * blockDim.x + threadIdx.x;
    if (e >= end) return;
    out[e] = (flag[src[e]] | flag[dst[e]]) ? 0.0f : val[e];
}

extern "C" void kernel_launch(void* const* d_in, const int* in_sizes, int n_in,
                              void* d_out, int out_size, void* d_ws, size_t ws_size,
                              hipStream_t stream)
{
    const int* edge_index = (const int*)d_in[0];
    const float* values   = (const float*)d_in[1];
    const int* flag       = (const int*)d_in[2];
    float* out            = (float*)d_out;

    const int E = in_sizes[1];
    const int N = in_sizes[2];
    const int* src = edge_index;
    const int* dst = edge_index + E;

    const int n_words = (N + 31) / 32;
    const size_t need = (size_t)n_words * sizeof(unsigned int);
    const size_t lds_bytes = (size_t)n_words * sizeof(unsigned int);

    if (ws_size >= need) {
        unsigned int* packed = (unsigned int*)d_ws;
        pack_flags<<<(n_words + 255) / 256, 256, 0, stream>>>(flag, packed, n_words, N);

        bool lds_ok = (lds_bytes <= 160 * 1024);
        if (lds_ok && lds_bytes > 64 * 1024) {
            lds_ok = (hipFuncSetAttribute(
                          (const void*)node_dropout_lds,
                          hipFuncAttributeMaxDynamicSharedMemorySize,
                          (int)lds_bytes) == hipSuccess);
        }

        const int n4 = E / 4;
        if (lds_ok) {
            if (n4 > 0) {
                node_dropout_lds<<<256, 1024, lds_bytes, stream>>>(
                    (const vint4*)src, (const vint4*)dst, (const vfloat4*)values,
                    packed, (vfloat4*)out, n_words, n4);
            }
        } else {
            if (n4 > 0) {
                node_dropout_packed<<<512, 256, 0, stream>>>(
                    (const vint4*)src, (const vint4*)dst, (const vfloat4*)values,
                    packed, (vfloat4*)out, n4);
            }
        }
        const int tail_begin = n4 * 4;
        if (tail_begin < E) {
            node_dropout_tail<<<(E - tail_begin + 255) / 256, 256, 0, stream>>>(
                src, dst, values, flag, out, tail_begin, E);
        }
    } else {
        node_dropout_tail<<<(E + 255) / 256, 256, 0, stream>>>(
            src, dst, values, flag, out, 0, E);
    }
}